// Round 1
// 562.413 us; speedup vs baseline: 1.2973x; 1.2973x over previous
//
#include <hip/hip_runtime.h>

#define N_NODES 50000
#define N_EDGES 800000
#define NODE_DIM 128
#define EDGE_DIM 64
#define HIDDEN 128
#define OUT_DIM 64

// ---- bucket multisplit geometry ----
#define NBKT 196          // ceil(50000/256) node buckets of 256 nodes
#define CAP 4864          // padded capacity per bucket (mean 4096, +12 sigma)
#define EPB 4096          // edges per block in bin_pairs
#define NBLK1 196         // ceil(800000/4096)

typedef unsigned short u16;
typedef unsigned int u32;

__device__ __forceinline__ float bflo(u32 u) { return __builtin_bit_cast(float, u << 16); }
__device__ __forceinline__ float bfhi(u32 u) { return __builtin_bit_cast(float, u & 0xFFFF0000u); }
__device__ __forceinline__ u32 pack2(float x, float y) {
    u32 a = __builtin_bit_cast(u32, x);
    a += 0x7FFFu + ((a >> 16) & 1u);
    u32 b = __builtin_bit_cast(u32, y);
    b += 0x7FFFu + ((b >> 16) & 1u);
    return (a >> 16) | (b & 0xFFFF0000u);
}

// ---------------------------------------------------------------------------
// cursor init: bucket write cursors start at b*CAP
// ---------------------------------------------------------------------------
__global__ void init_cursors(int* __restrict__ bcur, int* __restrict__ bcurm)
{
    int t = threadIdx.x;
    if (t < NBKT) { bcur[t] = t * CAP; bcurm[t] = t * CAP; }
}

// ---------------------------------------------------------------------------
// Pass 1: bin (val,key) pairs into padded per-bucket regions.
// prob 0: key=col[e], val=row[e].  prob 1: key=col[mcol[e]], val=mrow[e].
// Per-block LDS histogram -> one global atomic per (block,bucket) -> compact
// writes (~21-item contiguous runs) => ~1.3x write amp instead of 16x.
// ---------------------------------------------------------------------------
__global__ __launch_bounds__(256) void bin_pairs(
    const int* __restrict__ row, const int* __restrict__ col,
    const int* __restrict__ mrow, const int* __restrict__ mcol,
    int* __restrict__ bcur, int* __restrict__ bcurm,
    uint2* __restrict__ pairs, uint2* __restrict__ pairsm)
{
    int prob = (blockIdx.x >= NBLK1) ? 1 : 0;
    int blk = blockIdx.x - prob * NBLK1;
    int base = blk * EPB;
    int t = threadIdx.x;
    __shared__ int lh[NBKT];
    __shared__ int lbase[NBKT];
    __shared__ int lcur[NBKT];
    for (int i = t; i < NBKT; i += 256) { lh[i] = 0; lcur[i] = 0; }
    __syncthreads();
    int k[16], v[16];
    #pragma unroll
    for (int i = 0; i < 16; i++) {
        int idx = base + i * 256 + t;
        if (idx < N_EDGES) {
            if (!prob) { k[i] = col[idx]; v[i] = row[idx]; }
            else       { k[i] = col[mcol[idx]]; v[i] = mrow[idx]; }
            atomicAdd(&lh[k[i] >> 8], 1);
        } else {
            k[i] = -1; v[i] = 0;
        }
    }
    __syncthreads();
    int* gcur = prob ? bcurm : bcur;
    for (int i = t; i < NBKT; i += 256)
        lbase[i] = atomicAdd(&gcur[i], lh[i]);
    __syncthreads();
    uint2* PR = prob ? pairsm : pairs;
    #pragma unroll
    for (int i = 0; i < 16; i++) {
        if (k[i] >= 0) {
            int bk = k[i] >> 8;
            int p = lbase[bk] + atomicAdd(&lcur[bk], 1);
            if (p < (bk + 1) * CAP)           // overflow insurance
                PR[p] = make_uint2((u32)v[i], (u32)k[i]);
        }
    }
}

// ---------------------------------------------------------------------------
// Pass 2: one block per bucket. LDS histogram + scan over the bucket's 256
// nodes (replaces the global scan chain), emit offp/deg, scatter ids locally
// (all writes inside one ~19KB region owned by this block => 1 writeback/line).
// ---------------------------------------------------------------------------
__global__ __launch_bounds__(256) void bucket_fill(
    const uint2* __restrict__ pairs, const uint2* __restrict__ pairsm,
    const int* __restrict__ bcur, const int* __restrict__ bcurm,
    int* __restrict__ offp, int* __restrict__ deg, int* __restrict__ ids,
    int* __restrict__ offpm, int* __restrict__ degm, int* __restrict__ idsm)
{
    int prob = (blockIdx.x >= NBKT) ? 1 : 0;
    int b = blockIdx.x - prob * NBKT;
    const uint2* PR = prob ? pairsm : pairs;
    int cnt_total = (prob ? bcurm[b] : bcur[b]) - b * CAP;
    if (cnt_total > CAP) cnt_total = CAP;
    int n0 = b << 8;
    int nn = N_NODES - n0; if (nn > 256) nn = 256;
    __shared__ int hist[256];
    __shared__ int cur[256];
    __shared__ int wsum[4];
    __shared__ uint2 pbuf[CAP];
    int t = threadIdx.x;
    hist[t] = 0;
    __syncthreads();
    for (int i = t; i < cnt_total; i += 256) {
        uint2 pr = PR[(size_t)b * CAP + i];
        pbuf[i] = pr;
        atomicAdd(&hist[(int)pr.y - n0], 1);
    }
    __syncthreads();
    // exclusive scan of hist across 256 threads
    int h = hist[t];
    int x = h;
    int lane = t & 63, wid = t >> 6;
    for (int d = 1; d < 64; d <<= 1) {
        int u = __shfl_up(x, d, 64);
        if (lane >= d) x += u;
    }
    if (lane == 63) wsum[wid] = x;
    __syncthreads();
    int wex = 0;
    for (int i = 0; i < wid; i++) wex += wsum[i];
    int excl = wex + x - h;
    cur[t] = excl;
    if (t < nn) {
        if (!prob) { offp[n0 + t] = b * CAP + excl; deg[n0 + t] = h; }
        else       { offpm[n0 + t] = b * CAP + excl; degm[n0 + t] = h; }
    }
    __syncthreads();
    int* OI = prob ? idsm : ids;
    for (int i = t; i < cnt_total; i += 256) {
        uint2 pr = pbuf[i];
        int p = atomicAdd(&cur[(int)pr.y - n0], 1);
        OI[(size_t)b * CAP + p] = (int)pr.x;
    }
}

// ---------------------------------------------------------------------------
// Wcomb = We @ Wfc[128:256], bvec = be @ Wfc[128:256]
// ---------------------------------------------------------------------------
__global__ __launch_bounds__(256) void precompute_wcomb(
    const float* __restrict__ We, const float* __restrict__ be,
    const float* __restrict__ Wfc, float* __restrict__ Wcomb,
    float* __restrict__ bvec)
{
    int idx = blockIdx.x * 256 + threadIdx.x;
    if (idx < 64 * 64) {
        int k = idx >> 6, c = idx & 63;
        float s = 0.f;
        for (int h = 0; h < 128; h++)
            s = fmaf(We[k * 128 + h], Wfc[(128 + h) * 64 + c], s);
        Wcomb[idx] = s;
    } else if (idx < 64 * 64 + 64) {
        int c = idx - 64 * 64;
        float s = 0.f;
        for (int h = 0; h < 128; h++)
            s = fmaf(be[h], Wfc[(128 + h) * 64 + c], s);
        bvec[c] = s;
    }
}

// ---------------------------------------------------------------------------
// Micro-tiled GEMM, f32 A: P = A(Mx128) @ W(128x128) -> bf16.
// ---------------------------------------------------------------------------
__global__ __launch_bounds__(256) void gemm64_f32(
    const float* __restrict__ A, const float* __restrict__ W,
    u16* __restrict__ P, int M)
{
    __shared__ float As[64][132];
    __shared__ float Ws[64][128];
    int r0 = blockIdx.x * 64;
    for (int i = threadIdx.x; i < 64 * 32; i += 256) {
        int rr = i >> 5, cc = i & 31;
        int gr = r0 + rr;
        float4 v = make_float4(0.f, 0.f, 0.f, 0.f);
        if (gr < M) v = ((const float4*)(A + (size_t)gr * 128))[cc];
        *(float4*)(&As[rr][cc * 4]) = v;
    }
    float acc[4][8];
    #pragma unroll
    for (int r = 0; r < 4; r++)
        #pragma unroll
        for (int c = 0; c < 8; c++) acc[r][c] = 0.f;
    int rg = threadIdx.x >> 4;
    int cg = threadIdx.x & 15;
    for (int kb = 0; kb < 2; kb++) {
        __syncthreads();
        for (int i = threadIdx.x; i < 64 * 32; i += 256) {
            int rr = i >> 5, cc = i & 31;
            *(float4*)(&Ws[rr][cc * 4]) =
                ((const float4*)(W + (size_t)(kb * 64 + rr) * 128))[cc];
        }
        __syncthreads();
        #pragma unroll 8
        for (int k = 0; k < 64; k++) {
            float4 w0 = *(const float4*)(&Ws[k][cg * 4]);
            float4 w1 = *(const float4*)(&Ws[k][64 + cg * 4]);
            #pragma unroll
            for (int r = 0; r < 4; r++) {
                float a = As[rg * 4 + r][kb * 64 + k];
                acc[r][0] = fmaf(a, w0.x, acc[r][0]);
                acc[r][1] = fmaf(a, w0.y, acc[r][1]);
                acc[r][2] = fmaf(a, w0.z, acc[r][2]);
                acc[r][3] = fmaf(a, w0.w, acc[r][3]);
                acc[r][4] = fmaf(a, w1.x, acc[r][4]);
                acc[r][5] = fmaf(a, w1.y, acc[r][5]);
                acc[r][6] = fmaf(a, w1.z, acc[r][6]);
                acc[r][7] = fmaf(a, w1.w, acc[r][7]);
            }
        }
    }
    #pragma unroll
    for (int r = 0; r < 4; r++) {
        int gr = r0 + rg * 4 + r;
        if (gr < M) {
            uint2 o0, o1;
            o0.x = pack2(acc[r][0], acc[r][1]);
            o0.y = pack2(acc[r][2], acc[r][3]);
            o1.x = pack2(acc[r][4], acc[r][5]);
            o1.y = pack2(acc[r][6], acc[r][7]);
            ((uint2*)(P + (size_t)gr * 128))[cg] = o0;
            ((uint2*)(P + (size_t)gr * 128 + 64))[cg] = o1;
        }
    }
}

// ---------------------------------------------------------------------------
// Micro-tiled GEMM, bf16 A: P = A(Mx128 bf16) @ W(128x128) -> bf16.
// ---------------------------------------------------------------------------
__global__ __launch_bounds__(256) void gemm64_bf16(
    const u16* __restrict__ A, const float* __restrict__ W,
    u16* __restrict__ P, int M)
{
    __shared__ float As[64][132];
    __shared__ float Ws[64][128];
    int r0 = blockIdx.x * 64;
    for (int i = threadIdx.x; i < 64 * 32; i += 256) {
        int rr = i >> 5, cc = i & 31;
        int gr = r0 + rr;
        uint2 u = make_uint2(0u, 0u);
        if (gr < M) u = ((const uint2*)(A + (size_t)gr * 128))[cc];
        float4 v = make_float4(bflo(u.x), bfhi(u.x), bflo(u.y), bfhi(u.y));
        *(float4*)(&As[rr][cc * 4]) = v;
    }
    float acc[4][8];
    #pragma unroll
    for (int r = 0; r < 4; r++)
        #pragma unroll
        for (int c = 0; c < 8; c++) acc[r][c] = 0.f;
    int rg = threadIdx.x >> 4;
    int cg = threadIdx.x & 15;
    for (int kb = 0; kb < 2; kb++) {
        __syncthreads();
        for (int i = threadIdx.x; i < 64 * 32; i += 256) {
            int rr = i >> 5, cc = i & 31;
            *(float4*)(&Ws[rr][cc * 4]) =
                ((const float4*)(W + (size_t)(kb * 64 + rr) * 128))[cc];
        }
        __syncthreads();
        #pragma unroll 8
        for (int k = 0; k < 64; k++) {
            float4 w0 = *(const float4*)(&Ws[k][cg * 4]);
            float4 w1 = *(const float4*)(&Ws[k][64 + cg * 4]);
            #pragma unroll
            for (int r = 0; r < 4; r++) {
                float a = As[rg * 4 + r][kb * 64 + k];
                acc[r][0] = fmaf(a, w0.x, acc[r][0]);
                acc[r][1] = fmaf(a, w0.y, acc[r][1]);
                acc[r][2] = fmaf(a, w0.z, acc[r][2]);
                acc[r][3] = fmaf(a, w0.w, acc[r][3]);
                acc[r][4] = fmaf(a, w1.x, acc[r][4]);
                acc[r][5] = fmaf(a, w1.y, acc[r][5]);
                acc[r][6] = fmaf(a, w1.z, acc[r][6]);
                acc[r][7] = fmaf(a, w1.w, acc[r][7]);
            }
        }
    }
    #pragma unroll
    for (int r = 0; r < 4; r++) {
        int gr = r0 + rg * 4 + r;
        if (gr < M) {
            uint2 o0, o1;
            o0.x = pack2(acc[r][0], acc[r][1]);
            o0.y = pack2(acc[r][2], acc[r][3]);
            o1.x = pack2(acc[r][4], acc[r][5]);
            o1.y = pack2(acc[r][6], acc[r][7]);
            ((uint2*)(P + (size_t)gr * 128))[cg] = o0;
            ((uint2*)(P + (size_t)gr * 128 + 64))[cg] = o1;
        }
    }
}

// ---------------------------------------------------------------------------
// X[w] = relu(segsum(P) + deg*bias). Padded CSR: beg=offp[w], end=beg+deg[w].
// ---------------------------------------------------------------------------
__global__ __launch_bounds__(256) void agg_relu_bf16(
    const u16* __restrict__ P, const int* __restrict__ offp,
    const int* __restrict__ deg,
    const int* __restrict__ ids, const float* __restrict__ bias,
    u16* __restrict__ X, int M)
{
    int w = blockIdx.x * 4 + (threadIdx.x >> 6);
    if (w >= M) return;
    int lane = threadIdx.x & 63;
    int q = lane >> 4;
    int l = lane & 15;
    int beg = offp[w], end = beg + deg[w];
    const uint4* F = (const uint4*)P;
    float a0 = 0.f, a1 = 0.f, a2 = 0.f, a3 = 0.f,
          a4 = 0.f, a5 = 0.f, a6 = 0.f, a7 = 0.f;
    int i = beg;
    for (; i + 7 < end; i += 8) {
        int s0 = ids[i + q], s1 = ids[i + q + 4];
        uint4 v0 = F[(size_t)s0 * 16 + l];
        uint4 v1 = F[(size_t)s1 * 16 + l];
        a0 += bflo(v0.x) + bflo(v1.x); a1 += bfhi(v0.x) + bfhi(v1.x);
        a2 += bflo(v0.y) + bflo(v1.y); a3 += bfhi(v0.y) + bfhi(v1.y);
        a4 += bflo(v0.z) + bflo(v1.z); a5 += bfhi(v0.z) + bfhi(v1.z);
        a6 += bflo(v0.w) + bflo(v1.w); a7 += bfhi(v0.w) + bfhi(v1.w);
    }
    for (int j = i + q; j < end; j += 4) {
        uint4 v = F[(size_t)ids[j] * 16 + l];
        a0 += bflo(v.x); a1 += bfhi(v.x);
        a2 += bflo(v.y); a3 += bfhi(v.y);
        a4 += bflo(v.z); a5 += bfhi(v.z);
        a6 += bflo(v.w); a7 += bfhi(v.w);
    }
    a0 += __shfl_xor(a0, 32, 64); a1 += __shfl_xor(a1, 32, 64);
    a2 += __shfl_xor(a2, 32, 64); a3 += __shfl_xor(a3, 32, 64);
    a4 += __shfl_xor(a4, 32, 64); a5 += __shfl_xor(a5, 32, 64);
    a6 += __shfl_xor(a6, 32, 64); a7 += __shfl_xor(a7, 32, 64);
    a0 += __shfl_xor(a0, 16, 64); a1 += __shfl_xor(a1, 16, 64);
    a2 += __shfl_xor(a2, 16, 64); a3 += __shfl_xor(a3, 16, 64);
    a4 += __shfl_xor(a4, 16, 64); a5 += __shfl_xor(a5, 16, 64);
    a6 += __shfl_xor(a6, 16, 64); a7 += __shfl_xor(a7, 16, 64);
    if (q == 0) {
        float dg = (float)(end - beg);
        float4 b0 = ((const float4*)bias)[2 * l];
        float4 b1 = ((const float4*)bias)[2 * l + 1];
        a0 = fmaxf(fmaf(dg, b0.x, a0), 0.f);
        a1 = fmaxf(fmaf(dg, b0.y, a1), 0.f);
        a2 = fmaxf(fmaf(dg, b0.z, a2), 0.f);
        a3 = fmaxf(fmaf(dg, b0.w, a3), 0.f);
        a4 = fmaxf(fmaf(dg, b1.x, a4), 0.f);
        a5 = fmaxf(fmaf(dg, b1.y, a5), 0.f);
        a6 = fmaxf(fmaf(dg, b1.z, a6), 0.f);
        a7 = fmaxf(fmaf(dg, b1.w, a7), 0.f);
        uint4 o;
        o.x = pack2(a0, a1); o.y = pack2(a2, a3);
        o.z = pack2(a4, a5); o.w = pack2(a6, a7);
        ((uint4*)(X + (size_t)w * 128))[l] = o;
    }
}

// ---------------------------------------------------------------------------
// Epilogue agg: S[w] = x2[w] + segsum(x2) (bf16); Gg[w] = segsum_m(ef) (bf16).
// ---------------------------------------------------------------------------
__global__ __launch_bounds__(256) void agg_epilogue(
    const u16* __restrict__ X2, const float* __restrict__ ef,
    const int* __restrict__ offp, const int* __restrict__ deg,
    const int* __restrict__ ids,
    const int* __restrict__ offpm, const int* __restrict__ degm,
    const int* __restrict__ mids,
    u16* __restrict__ S, u16* __restrict__ Gg, int M)
{
    int w = blockIdx.x * 4 + (threadIdx.x >> 6);
    if (w >= M) return;
    int lane = threadIdx.x & 63;
    int q = lane >> 4;
    int l = lane & 15;
    // ---- node gather over X2 ----
    {
        int beg = offp[w], end = beg + deg[w];
        const uint4* F = (const uint4*)X2;
        float a0 = 0.f, a1 = 0.f, a2 = 0.f, a3 = 0.f,
              a4 = 0.f, a5 = 0.f, a6 = 0.f, a7 = 0.f;
        int i = beg;
        for (; i + 7 < end; i += 8) {
            int s0 = ids[i + q], s1 = ids[i + q + 4];
            uint4 v0 = F[(size_t)s0 * 16 + l];
            uint4 v1 = F[(size_t)s1 * 16 + l];
            a0 += bflo(v0.x) + bflo(v1.x); a1 += bfhi(v0.x) + bfhi(v1.x);
            a2 += bflo(v0.y) + bflo(v1.y); a3 += bfhi(v0.y) + bfhi(v1.y);
            a4 += bflo(v0.z) + bflo(v1.z); a5 += bfhi(v0.z) + bfhi(v1.z);
            a6 += bflo(v0.w) + bflo(v1.w); a7 += bfhi(v0.w) + bfhi(v1.w);
        }
        for (int j = i + q; j < end; j += 4) {
            uint4 v = F[(size_t)ids[j] * 16 + l];
            a0 += bflo(v.x); a1 += bfhi(v.x);
            a2 += bflo(v.y); a3 += bfhi(v.y);
            a4 += bflo(v.z); a5 += bfhi(v.z);
            a6 += bflo(v.w); a7 += bfhi(v.w);
        }
        a0 += __shfl_xor(a0, 32, 64); a1 += __shfl_xor(a1, 32, 64);
        a2 += __shfl_xor(a2, 32, 64); a3 += __shfl_xor(a3, 32, 64);
        a4 += __shfl_xor(a4, 32, 64); a5 += __shfl_xor(a5, 32, 64);
        a6 += __shfl_xor(a6, 32, 64); a7 += __shfl_xor(a7, 32, 64);
        a0 += __shfl_xor(a0, 16, 64); a1 += __shfl_xor(a1, 16, 64);
        a2 += __shfl_xor(a2, 16, 64); a3 += __shfl_xor(a3, 16, 64);
        a4 += __shfl_xor(a4, 16, 64); a5 += __shfl_xor(a5, 16, 64);
        a6 += __shfl_xor(a6, 16, 64); a7 += __shfl_xor(a7, 16, 64);
        if (q == 0) {
            uint4 own = F[(size_t)w * 16 + l];
            a0 += bflo(own.x); a1 += bfhi(own.x);
            a2 += bflo(own.y); a3 += bfhi(own.y);
            a4 += bflo(own.z); a5 += bfhi(own.z);
            a6 += bflo(own.w); a7 += bfhi(own.w);
            uint4 o;
            o.x = pack2(a0, a1); o.y = pack2(a2, a3);
            o.z = pack2(a4, a5); o.w = pack2(a6, a7);
            ((uint4*)(S + (size_t)w * 128))[l] = o;
        }
    }
    // ---- meta gather over ef (64 f32 rows = 16 float4) ----
    {
        int beg = offpm[w], end = beg + degm[w];
        const float4* E = (const float4*)ef;
        float g0 = 0.f, g1 = 0.f, g2 = 0.f, g3 = 0.f;
        int i = beg;
        for (; i + 7 < end; i += 8) {
            int s0 = mids[i + q], s1 = mids[i + q + 4];
            float4 v0 = E[(size_t)s0 * 16 + l];
            float4 v1 = E[(size_t)s1 * 16 + l];
            g0 += v0.x + v1.x; g1 += v0.y + v1.y;
            g2 += v0.z + v1.z; g3 += v0.w + v1.w;
        }
        for (int j = i + q; j < end; j += 4) {
            float4 v = E[(size_t)mids[j] * 16 + l];
            g0 += v.x; g1 += v.y; g2 += v.z; g3 += v.w;
        }
        g0 += __shfl_xor(g0, 32, 64); g1 += __shfl_xor(g1, 32, 64);
        g2 += __shfl_xor(g2, 32, 64); g3 += __shfl_xor(g3, 32, 64);
        g0 += __shfl_xor(g0, 16, 64); g1 += __shfl_xor(g1, 16, 64);
        g2 += __shfl_xor(g2, 16, 64); g3 += __shfl_xor(g3, 16, 64);
        if (q == 0) {
            uint2 o;
            o.x = pack2(g0, g1); o.y = pack2(g2, g3);
            ((uint2*)(Gg + (size_t)w * 64))[l] = o;
        }
    }
}

// ---------------------------------------------------------------------------
// out = S@Wfc_top + Gg@Wcomb + cnt⊗bvec + bfc. 64 rows/block, 4x4 tile/thread.
// ---------------------------------------------------------------------------
__global__ __launch_bounds__(256) void final_gemm(
    const u16* __restrict__ S, const u16* __restrict__ Gg,
    const int* __restrict__ degm, const float* __restrict__ Wfc,
    const float* __restrict__ Wcomb, const float* __restrict__ bvec,
    const float* __restrict__ bfc, float* __restrict__ out, int M)
{
    __shared__ float Ss[64][132];
    __shared__ float Gs[64][68];
    __shared__ float Ws[64][64];
    int r0 = blockIdx.x * 64;
    for (int i = threadIdx.x; i < 64 * 32; i += 256) {
        int rr = i >> 5, cc = i & 31;
        int gr = r0 + rr;
        uint2 u = make_uint2(0u, 0u);
        if (gr < M) u = ((const uint2*)(S + (size_t)gr * 128))[cc];
        float4 v = make_float4(bflo(u.x), bfhi(u.x), bflo(u.y), bfhi(u.y));
        *(float4*)(&Ss[rr][cc * 4]) = v;
    }
    for (int i = threadIdx.x; i < 64 * 16; i += 256) {
        int rr = i >> 4, cc = i & 15;
        int gr = r0 + rr;
        uint2 u = make_uint2(0u, 0u);
        if (gr < M) u = ((const uint2*)(Gg + (size_t)gr * 64))[cc];
        float4 v = make_float4(bflo(u.x), bfhi(u.x), bflo(u.y), bfhi(u.y));
        *(float4*)(&Gs[rr][cc * 4]) = v;
    }
    float acc[4][4];
    #pragma unroll
    for (int r = 0; r < 4; r++)
        #pragma unroll
        for (int c = 0; c < 4; c++) acc[r][c] = 0.f;
    int rg = threadIdx.x >> 4;
    int cg = threadIdx.x & 15;
    for (int ph = 0; ph < 3; ph++) {
        __syncthreads();
        const float* Wsrc = (ph < 2) ? (Wfc + (size_t)ph * 64 * 64) : Wcomb;
        for (int i = threadIdx.x; i < 64 * 16; i += 256) {
            int rr = i >> 4, cc = i & 15;
            *(float4*)(&Ws[rr][cc * 4]) = ((const float4*)(Wsrc + (size_t)rr * 64))[cc];
        }
        __syncthreads();
        #pragma unroll 8
        for (int k = 0; k < 64; k++) {
            float4 wv = *(const float4*)(&Ws[k][cg * 4]);
            #pragma unroll
            for (int r = 0; r < 4; r++) {
                float a = (ph < 2) ? Ss[rg * 4 + r][ph * 64 + k] : Gs[rg * 4 + r][k];
                acc[r][0] = fmaf(a, wv.x, acc[r][0]);
                acc[r][1] = fmaf(a, wv.y, acc[r][1]);
                acc[r][2] = fmaf(a, wv.z, acc[r][2]);
                acc[r][3] = fmaf(a, wv.w, acc[r][3]);
            }
        }
    }
    float4 bv = ((const float4*)bvec)[cg];
    float4 bf = ((const float4*)bfc)[cg];
    #pragma unroll
    for (int r = 0; r < 4; r++) {
        int gr = r0 + rg * 4 + r;
        if (gr < M) {
            float cnt = (float)degm[gr];
            float4 o;
            o.x = acc[r][0] + fmaf(cnt, bv.x, bf.x);
            o.y = acc[r][1] + fmaf(cnt, bv.y, bf.y);
            o.z = acc[r][2] + fmaf(cnt, bv.z, bf.z);
            o.w = acc[r][3] + fmaf(cnt, bv.w, bf.w);
            ((float4*)(out + (size_t)gr * 64))[cg] = o;
        }
    }
}

extern "C" void kernel_launch(void* const* d_in, const int* in_sizes, int n_in,
                              void* d_out, int out_size, void* d_ws, size_t ws_size,
                              hipStream_t stream)
{
    const float* nf  = (const float*)d_in[0];
    const int*   ei  = (const int*)d_in[1];
    const float* ef  = (const float*)d_in[2];
    const int*   emi = (const int*)d_in[3];
    const float* W1  = (const float*)d_in[4];
    const float* b1  = (const float*)d_in[5];
    const float* W2  = (const float*)d_in[6];
    const float* b2  = (const float*)d_in[7];
    const float* We  = (const float*)d_in[8];
    const float* be  = (const float*)d_in[9];
    const float* Wfc = (const float*)d_in[10];
    const float* bfc = (const float*)d_in[11];

    const int* row  = ei;
    const int* col  = ei + N_EDGES;
    const int* mrow = emi;
    const int* mcol = emi + N_EDGES;

    // ---- workspace layout ----
    u16* A  = (u16*)d_ws;                          // 50000*128 bf16
    u16* B  = A + (size_t)N_NODES * 128;
    u16* S  = B + (size_t)N_NODES * 128;
    u16* Gg = S + (size_t)N_NODES * 128;           // 50000*64
    uint2* pairs  = (uint2*)(Gg + (size_t)N_NODES * 64);   // NBKT*CAP
    uint2* pairsm = pairs + (size_t)NBKT * CAP;
    float* Wcomb = (float*)(pairsm + (size_t)NBKT * CAP);  // 64*64
    float* bvec  = Wcomb + 64 * 64;                        // 64
    int* offp  = (int*)(bvec + 64);                // N
    int* deg   = offp + N_NODES;                   // N
    int* offpm = deg + N_NODES;                    // N
    int* degm  = offpm + N_NODES;                  // N
    int* bcur  = degm + N_NODES;                   // 256
    int* bcurm = bcur + 256;                       // 256
    int* ids   = bcurm + 256;                      // NBKT*CAP
    int* idsm  = ids + (size_t)NBKT * CAP;         // NBKT*CAP

    precompute_wcomb<<<17, 256, 0, stream>>>(We, be, Wfc, Wcomb, bvec);

    // ---- CSR build via bucket multisplit (no global scan, no atomic scatter) ----
    init_cursors<<<1, 256, 0, stream>>>(bcur, bcurm);
    bin_pairs<<<2 * NBLK1, 256, 0, stream>>>(row, col, mrow, mcol,
                                             bcur, bcurm, pairs, pairsm);
    bucket_fill<<<2 * NBKT, 256, 0, stream>>>(pairs, pairsm, bcur, bcurm,
                                              offp, deg, ids, offpm, degm, idsm);

    // P1 = nf @ W1 (bf16)
    gemm64_f32<<<(N_NODES + 63) / 64, 256, 0, stream>>>(nf, W1, A, N_NODES);
    // x1 = relu(segsum(P1) + deg b1)
    agg_relu_bf16<<<(N_NODES + 3) / 4, 256, 0, stream>>>(A, offp, deg, ids, b1, B, N_NODES);
    // P2 = x1 @ W2
    gemm64_bf16<<<(N_NODES + 63) / 64, 256, 0, stream>>>(B, W2, A, N_NODES);
    // x2 = relu(segsum(P2) + deg b2)
    agg_relu_bf16<<<(N_NODES + 3) / 4, 256, 0, stream>>>(A, offp, deg, ids, b2, B, N_NODES);
    // S = x2 + agg(x2); Gg = agg_m(ef)
    agg_epilogue<<<(N_NODES + 3) / 4, 256, 0, stream>>>(
        B, ef, offp, deg, ids, offpm, degm, idsm, S, Gg, N_NODES);
    // out = S@Wfc_top + Gg@Wcomb + cnt bvec + bfc
    final_gemm<<<(N_NODES + 63) / 64, 256, 0, stream>>>(
        S, Gg, degm, Wfc, Wcomb, bvec, bfc, (float*)d_out, N_NODES);
}

// Round 3
// 493.091 us; speedup vs baseline: 1.4797x; 1.1406x over previous
//
#include <hip/hip_runtime.h>

#define N_NODES 50000
#define N_EDGES 800000
#define NODE_DIM 128
#define EDGE_DIM 64
#define HIDDEN 128
#define OUT_DIM 64

// ---- bucket multisplit geometry ----
#define NBKT 196          // ceil(50000/256) node buckets of 256 nodes
#define CAP 4864          // padded capacity per bucket (mean 4096, +12 sigma)
#define EPB 4096          // edges per block in bin_pairs
#define NBLK1 196         // ceil(800000/4096)

typedef unsigned short u16;
typedef unsigned int u32;
typedef __attribute__((ext_vector_type(8))) short bf16x8;
typedef __attribute__((ext_vector_type(4))) float f32x4;

__device__ __forceinline__ float bflo(u32 u) { return __builtin_bit_cast(float, u << 16); }
__device__ __forceinline__ float bfhi(u32 u) { return __builtin_bit_cast(float, u & 0xFFFF0000u); }
__device__ __forceinline__ u32 pack2(float x, float y) {
    u32 a = __builtin_bit_cast(u32, x);
    a += 0x7FFFu + ((a >> 16) & 1u);
    u32 b = __builtin_bit_cast(u32, y);
    b += 0x7FFFu + ((b >> 16) & 1u);
    return (a >> 16) | (b & 0xFFFF0000u);
}
__device__ __forceinline__ u16 bf16r(float x) {
    u32 a = __builtin_bit_cast(u32, x);
    a += 0x7FFFu + ((a >> 16) & 1u);
    return (u16)(a >> 16);
}

// ---------------------------------------------------------------------------
// pre1: Wcomb = We@Wfc[128:256], bvec = be@Wfc[128:256], W1t/W2t = bf16(W^T),
//       bucket cursor init. One launch.
// ---------------------------------------------------------------------------
__global__ __launch_bounds__(256) void pre1(
    const float* __restrict__ We, const float* __restrict__ be,
    const float* __restrict__ Wfc, const float* __restrict__ W1,
    const float* __restrict__ W2,
    float* __restrict__ Wcomb, float* __restrict__ bvec,
    short* __restrict__ W1t, short* __restrict__ W2t,
    int* __restrict__ bcur, int* __restrict__ bcurm)
{
    int idx = blockIdx.x * 256 + threadIdx.x;
    if (idx < 4096) {
        int k = idx >> 6, c = idx & 63;
        float s = 0.f;
        for (int h = 0; h < 128; h++)
            s = fmaf(We[k * 128 + h], Wfc[(128 + h) * 64 + c], s);
        Wcomb[idx] = s;
    } else if (idx < 4160) {
        int c = idx - 4096;
        float s = 0.f;
        for (int h = 0; h < 128; h++)
            s = fmaf(be[h], Wfc[(128 + h) * 64 + c], s);
        bvec[c] = s;
    } else if (idx < 20544) {
        int i = idx - 4160; int n = i >> 7, k = i & 127;
        W1t[n * 128 + k] = (short)bf16r(W1[k * 128 + n]);
    } else if (idx < 36928) {
        int i = idx - 20544; int n = i >> 7, k = i & 127;
        W2t[n * 128 + k] = (short)bf16r(W2[k * 128 + n]);
    } else if (idx < 37320) {
        int i = idx - 36928;
        if (i < 196) bcur[i] = i * CAP;
        else bcurm[i - 196] = (i - 196) * CAP;
    }
}

// ---------------------------------------------------------------------------
// pre2: Wft[n][k] (bf16, 64x192) = [Wfc_top^T | Wcomb^T]. Runs after pre1.
// ---------------------------------------------------------------------------
__global__ __launch_bounds__(256) void pre2(
    const float* __restrict__ Wfc, const float* __restrict__ Wcomb,
    short* __restrict__ Wft)
{
    int idx = blockIdx.x * 256 + threadIdx.x;
    if (idx < 64 * 192) {
        int n = idx / 192, k = idx - n * 192;
        float v = (k < 128) ? Wfc[k * 64 + n] : Wcomb[(k - 128) * 64 + n];
        Wft[n * 192 + k] = (short)bf16r(v);
    }
}

// ---------------------------------------------------------------------------
// Pass 1: bin packed (val|key) u32 into padded per-bucket regions.
// val fits 20 bits (<=800000), key-in-bucket 8 bits at bits 24..31.
// ---------------------------------------------------------------------------
__global__ __launch_bounds__(256) void bin_pairs(
    const int* __restrict__ row, const int* __restrict__ col,
    const int* __restrict__ mrow, const int* __restrict__ mcol,
    int* __restrict__ bcur, int* __restrict__ bcurm,
    u32* __restrict__ pairs, u32* __restrict__ pairsm)
{
    int prob = (blockIdx.x >= NBLK1) ? 1 : 0;
    int blk = blockIdx.x - prob * NBLK1;
    int base = blk * EPB;
    int t = threadIdx.x;
    __shared__ int lh[NBKT];
    __shared__ int lbase[NBKT];
    __shared__ int lcur[NBKT];
    for (int i = t; i < NBKT; i += 256) { lh[i] = 0; lcur[i] = 0; }
    __syncthreads();
    int k[16], v[16];
    #pragma unroll
    for (int i = 0; i < 16; i++) {
        int idx = base + i * 256 + t;
        if (idx < N_EDGES) {
            if (!prob) { k[i] = col[idx]; v[i] = row[idx]; }
            else       { k[i] = col[mcol[idx]]; v[i] = mrow[idx]; }
            atomicAdd(&lh[k[i] >> 8], 1);
        } else {
            k[i] = -1; v[i] = 0;
        }
    }
    __syncthreads();
    int* gcur = prob ? bcurm : bcur;
    for (int i = t; i < NBKT; i += 256)
        lbase[i] = atomicAdd(&gcur[i], lh[i]);
    __syncthreads();
    u32* PR = prob ? pairsm : pairs;
    #pragma unroll
    for (int i = 0; i < 16; i++) {
        if (k[i] >= 0) {
            int bk = k[i] >> 8;
            int p = lbase[bk] + atomicAdd(&lcur[bk], 1);
            if (p < (bk + 1) * CAP)           // overflow insurance
                PR[p] = (u32)v[i] | ((u32)(k[i] & 255) << 24);
        }
    }
}

// ---------------------------------------------------------------------------
// Pass 2: one block per bucket. LDS histogram + scan, emit offp/deg, scatter
// ids locally (all writes in one block-owned region => 1 writeback/line).
// ---------------------------------------------------------------------------
__global__ __launch_bounds__(256) void bucket_fill(
    const u32* __restrict__ pairs, const u32* __restrict__ pairsm,
    const int* __restrict__ bcur, const int* __restrict__ bcurm,
    int* __restrict__ offp, int* __restrict__ deg, int* __restrict__ ids,
    int* __restrict__ offpm, int* __restrict__ degm, int* __restrict__ idsm)
{
    int prob = (blockIdx.x >= NBKT) ? 1 : 0;
    int b = blockIdx.x - prob * NBKT;
    const u32* PR = prob ? pairsm : pairs;
    int cnt_total = (prob ? bcurm[b] : bcur[b]) - b * CAP;
    if (cnt_total > CAP) cnt_total = CAP;
    int n0 = b << 8;
    int nn = N_NODES - n0; if (nn > 256) nn = 256;
    __shared__ int hist[256];
    __shared__ int cur[256];
    __shared__ int wsum[4];
    __shared__ u32 pbuf[CAP];
    int t = threadIdx.x;
    hist[t] = 0;
    __syncthreads();
    for (int i = t; i < cnt_total; i += 256) {
        u32 pr = PR[(size_t)b * CAP + i];
        pbuf[i] = pr;
        atomicAdd(&hist[pr >> 24], 1);
    }
    __syncthreads();
    int h = hist[t];
    int x = h;
    int lane = t & 63, wid = t >> 6;
    for (int d = 1; d < 64; d <<= 1) {
        int u = __shfl_up(x, d, 64);
        if (lane >= d) x += u;
    }
    if (lane == 63) wsum[wid] = x;
    __syncthreads();
    int wex = 0;
    for (int i = 0; i < wid; i++) wex += wsum[i];
    int excl = wex + x - h;
    cur[t] = excl;
    if (t < nn) {
        if (!prob) { offp[n0 + t] = b * CAP + excl; deg[n0 + t] = h; }
        else       { offpm[n0 + t] = b * CAP + excl; degm[n0 + t] = h; }
    }
    __syncthreads();
    int* OI = prob ? idsm : ids;
    for (int i = t; i < cnt_total; i += 256) {
        u32 pr = pbuf[i];
        int p = atomicAdd(&cur[pr >> 24], 1);
        OI[(size_t)b * CAP + p] = (int)(pr & 0xFFFFFFu);
    }
}

// ---------------------------------------------------------------------------
// MFMA GEMM, f32 A: P = bf16(A) @ Wt^T -> bf16.  64 rows/block, 4 waves,
// wave = 32 rows x 64 cols. LDS XOR-swizzled (byte ^= (row&7)<<4).
// ---------------------------------------------------------------------------
__global__ __launch_bounds__(256) void gemm_mfma_f32(
    const float* __restrict__ A, const short* __restrict__ Wt,
    u16* __restrict__ P, int M)
{
    __shared__ short As[64 * 128];    // 16 KB
    __shared__ short Ws[128 * 128];   // 32 KB
    int t = threadIdx.x;
    int r0 = blockIdx.x * 64;
    for (int i = t; i < 64 * 32; i += 256) {
        int row = i >> 5, c4 = i & 31;
        int gr = r0 + row;
        float4 v = make_float4(0.f, 0.f, 0.f, 0.f);
        if (gr < M) v = ((const float4*)(A + (size_t)gr * 128))[c4];
        uint2 u; u.x = pack2(v.x, v.y); u.y = pack2(v.z, v.w);
        *(uint2*)((char*)As + row * 256 + ((c4 * 8) ^ ((row & 7) << 4))) = u;
    }
    for (int i = t; i < 128 * 16; i += 256) {
        int row = i >> 4, c16 = i & 15;
        uint4 u = *(const uint4*)((const char*)Wt + row * 256 + c16 * 16);
        *(uint4*)((char*)Ws + row * 256 + ((c16 * 16) ^ ((row & 7) << 4))) = u;
    }
    __syncthreads();
    int w = t >> 6, l = t & 63, lr = l & 15, q = l >> 4;
    int rh = (w & 1) * 32, ch = (w >> 1) * 64;
    f32x4 acc[2][4];
    #pragma unroll
    for (int rt = 0; rt < 2; rt++)
        #pragma unroll
        for (int ct = 0; ct < 4; ct++) acc[rt][ct] = (f32x4){0.f, 0.f, 0.f, 0.f};
    #pragma unroll
    for (int kk = 0; kk < 4; kk++) {
        int bo = kk * 64 + q * 16;
        bf16x8 a[2];
        #pragma unroll
        for (int rt = 0; rt < 2; rt++) {
            int ar = rh + rt * 16 + lr;
            a[rt] = *(const bf16x8*)((const char*)As + ar * 256 + (bo ^ ((ar & 7) << 4)));
        }
        #pragma unroll
        for (int ct = 0; ct < 4; ct++) {
            int br = ch + ct * 16 + lr;
            bf16x8 b = *(const bf16x8*)((const char*)Ws + br * 256 + (bo ^ ((br & 7) << 4)));
            acc[0][ct] = __builtin_amdgcn_mfma_f32_16x16x32_bf16(a[0], b, acc[0][ct], 0, 0, 0);
            acc[1][ct] = __builtin_amdgcn_mfma_f32_16x16x32_bf16(a[1], b, acc[1][ct], 0, 0, 0);
        }
    }
    #pragma unroll
    for (int rt = 0; rt < 2; rt++)
        #pragma unroll
        for (int reg = 0; reg < 4; reg++) {
            int gr = r0 + rh + rt * 16 + q * 4 + reg;
            if (gr < M) {
                #pragma unroll
                for (int ct = 0; ct < 4; ct++)
                    P[(size_t)gr * 128 + ch + ct * 16 + lr] = bf16r(acc[rt][ct][reg]);
            }
        }
}

// ---------------------------------------------------------------------------
// MFMA GEMM, bf16 A: P = A @ Wt^T -> bf16.
// ---------------------------------------------------------------------------
__global__ __launch_bounds__(256) void gemm_mfma_bf16(
    const u16* __restrict__ A, const short* __restrict__ Wt,
    u16* __restrict__ P, int M)
{
    __shared__ short As[64 * 128];
    __shared__ short Ws[128 * 128];
    int t = threadIdx.x;
    int r0 = blockIdx.x * 64;
    for (int i = t; i < 64 * 16; i += 256) {
        int row = i >> 4, c16 = i & 15;
        int gr = r0 + row;
        uint4 u = make_uint4(0u, 0u, 0u, 0u);
        if (gr < M) u = *(const uint4*)((const char*)A + (size_t)gr * 256 + c16 * 16);
        *(uint4*)((char*)As + row * 256 + ((c16 * 16) ^ ((row & 7) << 4))) = u;
    }
    for (int i = t; i < 128 * 16; i += 256) {
        int row = i >> 4, c16 = i & 15;
        uint4 u = *(const uint4*)((const char*)Wt + row * 256 + c16 * 16);
        *(uint4*)((char*)Ws + row * 256 + ((c16 * 16) ^ ((row & 7) << 4))) = u;
    }
    __syncthreads();
    int w = t >> 6, l = t & 63, lr = l & 15, q = l >> 4;
    int rh = (w & 1) * 32, ch = (w >> 1) * 64;
    f32x4 acc[2][4];
    #pragma unroll
    for (int rt = 0; rt < 2; rt++)
        #pragma unroll
        for (int ct = 0; ct < 4; ct++) acc[rt][ct] = (f32x4){0.f, 0.f, 0.f, 0.f};
    #pragma unroll
    for (int kk = 0; kk < 4; kk++) {
        int bo = kk * 64 + q * 16;
        bf16x8 a[2];
        #pragma unroll
        for (int rt = 0; rt < 2; rt++) {
            int ar = rh + rt * 16 + lr;
            a[rt] = *(const bf16x8*)((const char*)As + ar * 256 + (bo ^ ((ar & 7) << 4)));
        }
        #pragma unroll
        for (int ct = 0; ct < 4; ct++) {
            int br = ch + ct * 16 + lr;
            bf16x8 b = *(const bf16x8*)((const char*)Ws + br * 256 + (bo ^ ((br & 7) << 4)));
            acc[0][ct] = __builtin_amdgcn_mfma_f32_16x16x32_bf16(a[0], b, acc[0][ct], 0, 0, 0);
            acc[1][ct] = __builtin_amdgcn_mfma_f32_16x16x32_bf16(a[1], b, acc[1][ct], 0, 0, 0);
        }
    }
    #pragma unroll
    for (int rt = 0; rt < 2; rt++)
        #pragma unroll
        for (int reg = 0; reg < 4; reg++) {
            int gr = r0 + rh + rt * 16 + q * 4 + reg;
            if (gr < M) {
                #pragma unroll
                for (int ct = 0; ct < 4; ct++)
                    P[(size_t)gr * 128 + ch + ct * 16 + lr] = bf16r(acc[rt][ct][reg]);
            }
        }
}

// ---------------------------------------------------------------------------
// X[w] = relu(segsum(P) + deg*bias). Padded CSR: beg=offp[w], end=beg+deg[w].
// ---------------------------------------------------------------------------
__global__ __launch_bounds__(256) void agg_relu_bf16(
    const u16* __restrict__ P, const int* __restrict__ offp,
    const int* __restrict__ deg,
    const int* __restrict__ ids, const float* __restrict__ bias,
    u16* __restrict__ X, int M)
{
    int w = blockIdx.x * 4 + (threadIdx.x >> 6);
    if (w >= M) return;
    int lane = threadIdx.x & 63;
    int q = lane >> 4;
    int l = lane & 15;
    int beg = offp[w], end = beg + deg[w];
    const uint4* F = (const uint4*)P;
    float a0 = 0.f, a1 = 0.f, a2 = 0.f, a3 = 0.f,
          a4 = 0.f, a5 = 0.f, a6 = 0.f, a7 = 0.f;
    int i = beg;
    for (; i + 7 < end; i += 8) {
        int s0 = ids[i + q], s1 = ids[i + q + 4];
        uint4 v0 = F[(size_t)s0 * 16 + l];
        uint4 v1 = F[(size_t)s1 * 16 + l];
        a0 += bflo(v0.x) + bflo(v1.x); a1 += bfhi(v0.x) + bfhi(v1.x);
        a2 += bflo(v0.y) + bflo(v1.y); a3 += bfhi(v0.y) + bfhi(v1.y);
        a4 += bflo(v0.z) + bflo(v1.z); a5 += bfhi(v0.z) + bfhi(v1.z);
        a6 += bflo(v0.w) + bflo(v1.w); a7 += bfhi(v0.w) + bfhi(v1.w);
    }
    for (int j = i + q; j < end; j += 4) {
        uint4 v = F[(size_t)ids[j] * 16 + l];
        a0 += bflo(v.x); a1 += bfhi(v.x);
        a2 += bflo(v.y); a3 += bfhi(v.y);
        a4 += bflo(v.z); a5 += bfhi(v.z);
        a6 += bflo(v.w); a7 += bfhi(v.w);
    }
    a0 += __shfl_xor(a0, 32, 64); a1 += __shfl_xor(a1, 32, 64);
    a2 += __shfl_xor(a2, 32, 64); a3 += __shfl_xor(a3, 32, 64);
    a4 += __shfl_xor(a4, 32, 64); a5 += __shfl_xor(a5, 32, 64);
    a6 += __shfl_xor(a6, 32, 64); a7 += __shfl_xor(a7, 32, 64);
    a0 += __shfl_xor(a0, 16, 64); a1 += __shfl_xor(a1, 16, 64);
    a2 += __shfl_xor(a2, 16, 64); a3 += __shfl_xor(a3, 16, 64);
    a4 += __shfl_xor(a4, 16, 64); a5 += __shfl_xor(a5, 16, 64);
    a6 += __shfl_xor(a6, 16, 64); a7 += __shfl_xor(a7, 16, 64);
    if (q == 0) {
        float dg = (float)(end - beg);
        float4 b0 = ((const float4*)bias)[2 * l];
        float4 b1 = ((const float4*)bias)[2 * l + 1];
        a0 = fmaxf(fmaf(dg, b0.x, a0), 0.f);
        a1 = fmaxf(fmaf(dg, b0.y, a1), 0.f);
        a2 = fmaxf(fmaf(dg, b0.z, a2), 0.f);
        a3 = fmaxf(fmaf(dg, b0.w, a3), 0.f);
        a4 = fmaxf(fmaf(dg, b1.x, a4), 0.f);
        a5 = fmaxf(fmaf(dg, b1.y, a5), 0.f);
        a6 = fmaxf(fmaf(dg, b1.z, a6), 0.f);
        a7 = fmaxf(fmaf(dg, b1.w, a7), 0.f);
        uint4 o;
        o.x = pack2(a0, a1); o.y = pack2(a2, a3);
        o.z = pack2(a4, a5); o.w = pack2(a6, a7);
        ((uint4*)(X + (size_t)w * 128))[l] = o;
    }
}

// ---------------------------------------------------------------------------
// Epilogue agg: S[w] = x2[w] + segsum(x2) (bf16); Gg[w] = segsum_m(ef) (bf16).
// ---------------------------------------------------------------------------
__global__ __launch_bounds__(256) void agg_epilogue(
    const u16* __restrict__ X2, const float* __restrict__ ef,
    const int* __restrict__ offp, const int* __restrict__ deg,
    const int* __restrict__ ids,
    const int* __restrict__ offpm, const int* __restrict__ degm,
    const int* __restrict__ mids,
    u16* __restrict__ S, u16* __restrict__ Gg, int M)
{
    int w = blockIdx.x * 4 + (threadIdx.x >> 6);
    if (w >= M) return;
    int lane = threadIdx.x & 63;
    int q = lane >> 4;
    int l = lane & 15;
    {
        int beg = offp[w], end = beg + deg[w];
        const uint4* F = (const uint4*)X2;
        float a0 = 0.f, a1 = 0.f, a2 = 0.f, a3 = 0.f,
              a4 = 0.f, a5 = 0.f, a6 = 0.f, a7 = 0.f;
        int i = beg;
        for (; i + 7 < end; i += 8) {
            int s0 = ids[i + q], s1 = ids[i + q + 4];
            uint4 v0 = F[(size_t)s0 * 16 + l];
            uint4 v1 = F[(size_t)s1 * 16 + l];
            a0 += bflo(v0.x) + bflo(v1.x); a1 += bfhi(v0.x) + bfhi(v1.x);
            a2 += bflo(v0.y) + bflo(v1.y); a3 += bfhi(v0.y) + bfhi(v1.y);
            a4 += bflo(v0.z) + bflo(v1.z); a5 += bfhi(v0.z) + bfhi(v1.z);
            a6 += bflo(v0.w) + bflo(v1.w); a7 += bfhi(v0.w) + bfhi(v1.w);
        }
        for (int j = i + q; j < end; j += 4) {
            uint4 v = F[(size_t)ids[j] * 16 + l];
            a0 += bflo(v.x); a1 += bfhi(v.x);
            a2 += bflo(v.y); a3 += bfhi(v.y);
            a4 += bflo(v.z); a5 += bfhi(v.z);
            a6 += bflo(v.w); a7 += bfhi(v.w);
        }
        a0 += __shfl_xor(a0, 32, 64); a1 += __shfl_xor(a1, 32, 64);
        a2 += __shfl_xor(a2, 32, 64); a3 += __shfl_xor(a3, 32, 64);
        a4 += __shfl_xor(a4, 32, 64); a5 += __shfl_xor(a5, 32, 64);
        a6 += __shfl_xor(a6, 32, 64); a7 += __shfl_xor(a7, 32, 64);
        a0 += __shfl_xor(a0, 16, 64); a1 += __shfl_xor(a1, 16, 64);
        a2 += __shfl_xor(a2, 16, 64); a3 += __shfl_xor(a3, 16, 64);
        a4 += __shfl_xor(a4, 16, 64); a5 += __shfl_xor(a5, 16, 64);
        a6 += __shfl_xor(a6, 16, 64); a7 += __shfl_xor(a7, 16, 64);
        if (q == 0) {
            uint4 own = F[(size_t)w * 16 + l];
            a0 += bflo(own.x); a1 += bfhi(own.x);
            a2 += bflo(own.y); a3 += bfhi(own.y);
            a4 += bflo(own.z); a5 += bfhi(own.z);
            a6 += bflo(own.w); a7 += bfhi(own.w);
            uint4 o;
            o.x = pack2(a0, a1); o.y = pack2(a2, a3);
            o.z = pack2(a4, a5); o.w = pack2(a6, a7);
            ((uint4*)(S + (size_t)w * 128))[l] = o;
        }
    }
    {
        int beg = offpm[w], end = beg + degm[w];
        const float4* E = (const float4*)ef;
        float g0 = 0.f, g1 = 0.f, g2 = 0.f, g3 = 0.f;
        int i = beg;
        for (; i + 7 < end; i += 8) {
            int s0 = mids[i + q], s1 = mids[i + q + 4];
            float4 v0 = E[(size_t)s0 * 16 + l];
            float4 v1 = E[(size_t)s1 * 16 + l];
            g0 += v0.x + v1.x; g1 += v0.y + v1.y;
            g2 += v0.z + v1.z; g3 += v0.w + v1.w;
        }
        for (int j = i + q; j < end; j += 4) {
            float4 v = E[(size_t)mids[j] * 16 + l];
            g0 += v.x; g1 += v.y; g2 += v.z; g3 += v.w;
        }
        g0 += __shfl_xor(g0, 32, 64); g1 += __shfl_xor(g1, 32, 64);
        g2 += __shfl_xor(g2, 32, 64); g3 += __shfl_xor(g3, 32, 64);
        g0 += __shfl_xor(g0, 16, 64); g1 += __shfl_xor(g1, 16, 64);
        g2 += __shfl_xor(g2, 16, 64); g3 += __shfl_xor(g3, 16, 64);
        if (q == 0) {
            uint2 o;
            o.x = pack2(g0, g1); o.y = pack2(g2, g3);
            ((uint2*)(Gg + (size_t)w * 64))[l] = o;
        }
    }
}

// ---------------------------------------------------------------------------
// final MFMA GEMM: out = [S|Gg](64x192 bf16) @ Wft^T + cnt*bvec + bfc (f32).
// 64 rows/block, 4 waves, wave = 32 rows x 32 cols, K=192.
// ---------------------------------------------------------------------------
__global__ __launch_bounds__(256) void final_mfma(
    const u16* __restrict__ S, const u16* __restrict__ Gg,
    const int* __restrict__ degm, const short* __restrict__ Wft,
    const float* __restrict__ bvec, const float* __restrict__ bfc,
    float* __restrict__ out, int M)
{
    __shared__ short As[64 * 192];   // 24 KB, row stride 384B
    __shared__ short Ws[64 * 192];   // 24 KB
    int t = threadIdx.x;
    int r0 = blockIdx.x * 64;
    for (int i = t; i < 64 * 16; i += 256) {      // S half: bytes [0,256)/row
        int row = i >> 4, c16 = i & 15;
        int gr = r0 + row;
        uint4 u = make_uint4(0u, 0u, 0u, 0u);
        if (gr < M) u = *(const uint4*)((const char*)S + (size_t)gr * 256 + c16 * 16);
        *(uint4*)((char*)As + row * 384 + ((c16 * 16) ^ ((row & 7) << 4))) = u;
    }
    for (int i = t; i < 64 * 8; i += 256) {       // Gg half: bytes [256,384)/row
        int row = i >> 3, c16 = i & 7;
        int gr = r0 + row;
        uint4 u = make_uint4(0u, 0u, 0u, 0u);
        if (gr < M) u = *(const uint4*)((const char*)Gg + (size_t)gr * 128 + c16 * 16);
        *(uint4*)((char*)As + row * 384 + ((256 + c16 * 16) ^ ((row & 7) << 4))) = u;
    }
    for (int i = t; i < 64 * 24; i += 256) {      // Wft: 24 chunks/row (384B)
        int row = i / 24, c16 = i - row * 24;
        uint4 u = *(const uint4*)((const char*)Wft + row * 384 + c16 * 16);
        *(uint4*)((char*)Ws + row * 384 + ((c16 * 16) ^ ((row & 7) << 4))) = u;
    }
    __syncthreads();
    int w = t >> 6, l = t & 63, lr = l & 15, q = l >> 4;
    int rh = (w & 1) * 32, ch = (w >> 1) * 32;
    f32x4 acc[2][2];
    #pragma unroll
    for (int rt = 0; rt < 2; rt++)
        #pragma unroll
        for (int ct = 0; ct < 2; ct++) acc[rt][ct] = (f32x4){0.f, 0.f, 0.f, 0.f};
    #pragma unroll
    for (int kk = 0; kk < 6; kk++) {
        int bo = kk * 64 + q * 16;
        bf16x8 a[2];
        #pragma unroll
        for (int rt = 0; rt < 2; rt++) {
            int ar = rh + rt * 16 + lr;
            a[rt] = *(const bf16x8*)((const char*)As + ar * 384 + (bo ^ ((ar & 7) << 4)));
        }
        #pragma unroll
        for (int ct = 0; ct < 2; ct++) {
            int br = ch + ct * 16 + lr;
            bf16x8 b = *(const bf16x8*)((const char*)Ws + br * 384 + (bo ^ ((br & 7) << 4)));
            acc[0][ct] = __builtin_amdgcn_mfma_f32_16x16x32_bf16(a[0], b, acc[0][ct], 0, 0, 0);
            acc[1][ct] = __builtin_amdgcn_mfma_f32_16x16x32_bf16(a[1], b, acc[1][ct], 0, 0, 0);
        }
    }
    float bv0 = bvec[ch + lr], bv1 = bvec[ch + 16 + lr];
    float bf0 = bfc[ch + lr],  bf1 = bfc[ch + 16 + lr];
    #pragma unroll
    for (int rt = 0; rt < 2; rt++)
        #pragma unroll
        for (int reg = 0; reg < 4; reg++) {
            int gr = r0 + rh + rt * 16 + q * 4 + reg;
            if (gr < M) {
                float cnt = (float)degm[gr];
                out[(size_t)gr * 64 + ch + lr]      = acc[rt][0][reg] + fmaf(cnt, bv0, bf0);
                out[(size_t)gr * 64 + ch + 16 + lr] = acc[rt][1][reg] + fmaf(cnt, bv1, bf1);
            }
        }
}

extern "C" void kernel_launch(void* const* d_in, const int* in_sizes, int n_in,
                              void* d_out, int out_size, void* d_ws, size_t ws_size,
                              hipStream_t stream)
{
    const float* nf  = (const float*)d_in[0];
    const int*   ei  = (const int*)d_in[1];
    const float* ef  = (const float*)d_in[2];
    const int*   emi = (const int*)d_in[3];
    const float* W1  = (const float*)d_in[4];
    const float* b1  = (const float*)d_in[5];
    const float* W2  = (const float*)d_in[6];
    const float* b2  = (const float*)d_in[7];
    const float* We  = (const float*)d_in[8];
    const float* be  = (const float*)d_in[9];
    const float* Wfc = (const float*)d_in[10];
    const float* bfc = (const float*)d_in[11];

    const int* row  = ei;
    const int* col  = ei + N_EDGES;
    const int* mrow = emi;
    const int* mcol = emi + N_EDGES;

    // ---- workspace layout (16B alignment maintained for short/uint4 blocks) ----
    u16* A  = (u16*)d_ws;                          // 50000*128 bf16
    u16* B  = A + (size_t)N_NODES * 128;
    u16* S  = B + (size_t)N_NODES * 128;
    u16* Gg = S + (size_t)N_NODES * 128;           // 50000*64
    u32* pairs  = (u32*)(Gg + (size_t)N_NODES * 64);       // NBKT*CAP
    u32* pairsm = pairs + (size_t)NBKT * CAP;
    float* Wcomb = (float*)(pairsm + (size_t)NBKT * CAP);  // 64*64
    float* bvec  = Wcomb + 64 * 64;                        // 64
    short* W1t = (short*)(bvec + 64);              // 128*128 bf16
    short* W2t = W1t + 128 * 128;
    short* Wft = W2t + 128 * 128;                  // 64*192 bf16
    int* offp  = (int*)(Wft + 64 * 192);           // N
    int* deg   = offp + N_NODES;
    int* offpm = deg + N_NODES;
    int* degm  = offpm + N_NODES;
    int* bcur  = degm + N_NODES;                   // 256
    int* bcurm = bcur + 256;
    int* ids   = bcurm + 256;                      // NBKT*CAP
    int* idsm  = ids + (size_t)NBKT * CAP;

    // weights precompute + cursor init
    pre1<<<146, 256, 0, stream>>>(We, be, Wfc, W1, W2, Wcomb, bvec, W1t, W2t, bcur, bcurm);

    // CSR build via bucket multisplit
    bin_pairs<<<2 * NBLK1, 256, 0, stream>>>(row, col, mrow, mcol,
                                             bcur, bcurm, pairs, pairsm);
    bucket_fill<<<2 * NBKT, 256, 0, stream>>>(pairs, pairsm, bcur, bcurm,
                                              offp, deg, ids, offpm, degm, idsm);
    pre2<<<48, 256, 0, stream>>>(Wfc, Wcomb, Wft);

    // P1 = nf @ W1 (bf16, MFMA)
    gemm_mfma_f32<<<(N_NODES + 63) / 64, 256, 0, stream>>>(nf, W1t, A, N_NODES);
    // x1 = relu(segsum(P1) + deg b1)
    agg_relu_bf16<<<(N_NODES + 3) / 4, 256, 0, stream>>>(A, offp, deg, ids, b1, B, N_NODES);
    // P2 = x1 @ W2 (MFMA)
    gemm_mfma_bf16<<<(N_NODES + 63) / 64, 256, 0, stream>>>(B, W2t, A, N_NODES);
    // x2 = relu(segsum(P2) + deg b2)
    agg_relu_bf16<<<(N_NODES + 3) / 4, 256, 0, stream>>>(A, offp, deg, ids, b2, B, N_NODES);
    // S = x2 + agg(x2); Gg = agg_m(ef)
    agg_epilogue<<<(N_NODES + 3) / 4, 256, 0, stream>>>(
        B, ef, offp, deg, ids, offpm, degm, idsm, S, Gg, N_NODES);
    // out = [S|Gg] @ Wft^T + cnt bvec + bfc (MFMA)
    final_mfma<<<(N_NODES + 63) / 64, 256, 0, stream>>>(
        S, Gg, degm, Wft, bvec, bfc, (float*)d_out, N_NODES);
}

// Round 6
// 482.147 us; speedup vs baseline: 1.5133x; 1.0227x over previous
//
#include <hip/hip_runtime.h>

#define N_NODES 50000
#define N_EDGES 800000
#define NODE_DIM 128
#define EDGE_DIM 64
#define HIDDEN 128
#define OUT_DIM 64

// ---- bucket multisplit geometry ----
#define NBKT 196          // ceil(50000/256) node buckets of 256 nodes
#define CAP 4864          // padded capacity per bucket (mean 4096, +12 sigma)
#define EPB 4096          // edges per block in bin_pairs
#define NBLK1 196         // ceil(800000/4096)

typedef unsigned short u16;
typedef unsigned int u32;
typedef __attribute__((ext_vector_type(8))) short bf16x8;
typedef __attribute__((ext_vector_type(4))) float f32x4;

__device__ __forceinline__ float bflo(u32 u) { return __builtin_bit_cast(float, u << 16); }
__device__ __forceinline__ float bfhi(u32 u) { return __builtin_bit_cast(float, u & 0xFFFF0000u); }
__device__ __forceinline__ u32 pack2(float x, float y) {
    u32 a = __builtin_bit_cast(u32, x);
    a += 0x7FFFu + ((a >> 16) & 1u);
    u32 b = __builtin_bit_cast(u32, y);
    b += 0x7FFFu + ((b >> 16) & 1u);
    return (a >> 16) | (b & 0xFFFF0000u);
}
__device__ __forceinline__ u16 bf16r(float x) {
    u32 a = __builtin_bit_cast(u32, x);
    a += 0x7FFFu + ((a >> 16) & 1u);
    return (u16)(a >> 16);
}

// ---------------------------------------------------------------------------
// pre1: Wcomb = We@Wfc[128:256], bvec = be@Wfc[128:256], W1t/W2t = bf16(W^T),
//       bucket cursor init. One launch.
// ---------------------------------------------------------------------------
__global__ __launch_bounds__(256) void pre1(
    const float* __restrict__ We, const float* __restrict__ be,
    const float* __restrict__ Wfc, const float* __restrict__ W1,
    const float* __restrict__ W2,
    float* __restrict__ Wcomb, float* __restrict__ bvec,
    short* __restrict__ W1t, short* __restrict__ W2t,
    int* __restrict__ bcur, int* __restrict__ bcurm)
{
    int idx = blockIdx.x * 256 + threadIdx.x;
    if (idx < 4096) {
        int k = idx >> 6, c = idx & 63;
        float s = 0.f;
        for (int h = 0; h < 128; h++)
            s = fmaf(We[k * 128 + h], Wfc[(128 + h) * 64 + c], s);
        Wcomb[idx] = s;
    } else if (idx < 4160) {
        int c = idx - 4096;
        float s = 0.f;
        for (int h = 0; h < 128; h++)
            s = fmaf(be[h], Wfc[(128 + h) * 64 + c], s);
        bvec[c] = s;
    } else if (idx < 20544) {
        int i = idx - 4160; int n = i >> 7, k = i & 127;
        W1t[n * 128 + k] = (short)bf16r(W1[k * 128 + n]);
    } else if (idx < 36928) {
        int i = idx - 20544; int n = i >> 7, k = i & 127;
        W2t[n * 128 + k] = (short)bf16r(W2[k * 128 + n]);
    } else if (idx < 37320) {
        int i = idx - 36928;
        if (i < 196) bcur[i] = i * CAP;
        else bcurm[i - 196] = (i - 196) * CAP;
    }
}

// ---------------------------------------------------------------------------
// pre2: Wft[n][k] (bf16, 64x192) = [Wfc_top^T | Wcomb^T]. Runs after pre1.
// ---------------------------------------------------------------------------
__global__ __launch_bounds__(256) void pre2(
    const float* __restrict__ Wfc, const float* __restrict__ Wcomb,
    short* __restrict__ Wft)
{
    int idx = blockIdx.x * 256 + threadIdx.x;
    if (idx < 64 * 192) {
        int n = idx / 192, k = idx - n * 192;
        float v = (k < 128) ? Wfc[k * 64 + n] : Wcomb[(k - 128) * 64 + n];
        Wft[n * 192 + k] = (short)bf16r(v);
    }
}

// ---------------------------------------------------------------------------
// Pass 1: bin packed (val|key) u32 into padded per-bucket regions.
// ---------------------------------------------------------------------------
__global__ __launch_bounds__(256) void bin_pairs(
    const int* __restrict__ row, const int* __restrict__ col,
    const int* __restrict__ mrow, const int* __restrict__ mcol,
    int* __restrict__ bcur, int* __restrict__ bcurm,
    u32* __restrict__ pairs, u32* __restrict__ pairsm)
{
    int prob = (blockIdx.x >= NBLK1) ? 1 : 0;
    int blk = blockIdx.x - prob * NBLK1;
    int base = blk * EPB;
    int t = threadIdx.x;
    __shared__ int lh[NBKT];
    __shared__ int lbase[NBKT];
    __shared__ int lcur[NBKT];
    for (int i = t; i < NBKT; i += 256) { lh[i] = 0; lcur[i] = 0; }
    __syncthreads();
    int k[16], v[16];
    #pragma unroll
    for (int i = 0; i < 16; i++) {
        int idx = base + i * 256 + t;
        if (idx < N_EDGES) {
            if (!prob) { k[i] = col[idx]; v[i] = row[idx]; }
            else       { k[i] = col[mcol[idx]]; v[i] = mrow[idx]; }
            atomicAdd(&lh[k[i] >> 8], 1);
        } else {
            k[i] = -1; v[i] = 0;
        }
    }
    __syncthreads();
    int* gcur = prob ? bcurm : bcur;
    for (int i = t; i < NBKT; i += 256)
        lbase[i] = atomicAdd(&gcur[i], lh[i]);
    __syncthreads();
    u32* PR = prob ? pairsm : pairs;
    #pragma unroll
    for (int i = 0; i < 16; i++) {
        if (k[i] >= 0) {
            int bk = k[i] >> 8;
            int p = lbase[bk] + atomicAdd(&lcur[bk], 1);
            if (p < (bk + 1) * CAP)           // overflow insurance
                PR[p] = (u32)v[i] | ((u32)(k[i] & 255) << 24);
        }
    }
}

// ---------------------------------------------------------------------------
// Pass 2: one block per bucket. LDS histogram + scan, emit offp/deg, scatter
// ids locally.
// ---------------------------------------------------------------------------
__global__ __launch_bounds__(256) void bucket_fill(
    const u32* __restrict__ pairs, const u32* __restrict__ pairsm,
    const int* __restrict__ bcur, const int* __restrict__ bcurm,
    int* __restrict__ offp, int* __restrict__ deg, int* __restrict__ ids,
    int* __restrict__ offpm, int* __restrict__ degm, int* __restrict__ idsm)
{
    int prob = (blockIdx.x >= NBKT) ? 1 : 0;
    int b = blockIdx.x - prob * NBKT;
    const u32* PR = prob ? pairsm : pairs;
    int cnt_total = (prob ? bcurm[b] : bcur[b]) - b * CAP;
    if (cnt_total > CAP) cnt_total = CAP;
    int n0 = b << 8;
    int nn = N_NODES - n0; if (nn > 256) nn = 256;
    __shared__ int hist[256];
    __shared__ int cur[256];
    __shared__ int wsum[4];
    __shared__ u32 pbuf[CAP];
    int t = threadIdx.x;
    hist[t] = 0;
    __syncthreads();
    for (int i = t; i < cnt_total; i += 256) {
        u32 pr = PR[(size_t)b * CAP + i];
        pbuf[i] = pr;
        atomicAdd(&hist[pr >> 24], 1);
    }
    __syncthreads();
    int h = hist[t];
    int x = h;
    int lane = t & 63, wid = t >> 6;
    for (int d = 1; d < 64; d <<= 1) {
        int u = __shfl_up(x, d, 64);
        if (lane >= d) x += u;
    }
    if (lane == 63) wsum[wid] = x;
    __syncthreads();
    int wex = 0;
    for (int i = 0; i < wid; i++) wex += wsum[i];
    int excl = wex + x - h;
    cur[t] = excl;
    if (t < nn) {
        if (!prob) { offp[n0 + t] = b * CAP + excl; deg[n0 + t] = h; }
        else       { offpm[n0 + t] = b * CAP + excl; degm[n0 + t] = h; }
    }
    __syncthreads();
    int* OI = prob ? idsm : ids;
    for (int i = t; i < cnt_total; i += 256) {
        u32 pr = pbuf[i];
        int p = atomicAdd(&cur[pr >> 24], 1);
        OI[(size_t)b * CAP + p] = (int)(pr & 0xFFFFFFu);
    }
}

// ---------------------------------------------------------------------------
// MFMA GEMM, f32 A: P = bf16(A) @ Wt^T -> bf16.  64 rows/block, 4 waves,
// wave = 32 rows x 64 cols. LDS XOR-swizzled (byte ^= (row&7)<<4).
// ---------------------------------------------------------------------------
__global__ __launch_bounds__(256) void gemm_mfma_f32(
    const float* __restrict__ A, const short* __restrict__ Wt,
    u16* __restrict__ P, int M)
{
    __shared__ short As[64 * 128];    // 16 KB
    __shared__ short Ws[128 * 128];   // 32 KB
    int t = threadIdx.x;
    int r0 = blockIdx.x * 64;
    for (int i = t; i < 64 * 32; i += 256) {
        int row = i >> 5, c4 = i & 31;
        int gr = r0 + row;
        float4 v = make_float4(0.f, 0.f, 0.f, 0.f);
        if (gr < M) v = ((const float4*)(A + (size_t)gr * 128))[c4];
        uint2 u; u.x = pack2(v.x, v.y); u.y = pack2(v.z, v.w);
        *(uint2*)((char*)As + row * 256 + ((c4 * 8) ^ ((row & 7) << 4))) = u;
    }
    for (int i = t; i < 128 * 16; i += 256) {
        int row = i >> 4, c16 = i & 15;
        uint4 u = *(const uint4*)((const char*)Wt + row * 256 + c16 * 16);
        *(uint4*)((char*)Ws + row * 256 + ((c16 * 16) ^ ((row & 7) << 4))) = u;
    }
    __syncthreads();
    int w = t >> 6, l = t & 63, lr = l & 15, q = l >> 4;
    int rh = (w & 1) * 32, ch = (w >> 1) * 64;
    f32x4 acc[2][4];
    #pragma unroll
    for (int rt = 0; rt < 2; rt++)
        #pragma unroll
        for (int ct = 0; ct < 4; ct++) acc[rt][ct] = (f32x4){0.f, 0.f, 0.f, 0.f};
    #pragma unroll
    for (int kk = 0; kk < 4; kk++) {
        int bo = kk * 64 + q * 16;
        bf16x8 a[2];
        #pragma unroll
        for (int rt = 0; rt < 2; rt++) {
            int ar = rh + rt * 16 + lr;
            a[rt] = *(const bf16x8*)((const char*)As + ar * 256 + (bo ^ ((ar & 7) << 4)));
        }
        #pragma unroll
        for (int ct = 0; ct < 4; ct++) {
            int br = ch + ct * 16 + lr;
            bf16x8 b = *(const bf16x8*)((const char*)Ws + br * 256 + (bo ^ ((br & 7) << 4)));
            acc[0][ct] = __builtin_amdgcn_mfma_f32_16x16x32_bf16(a[0], b, acc[0][ct], 0, 0, 0);
            acc[1][ct] = __builtin_amdgcn_mfma_f32_16x16x32_bf16(a[1], b, acc[1][ct], 0, 0, 0);
        }
    }
    #pragma unroll
    for (int rt = 0; rt < 2; rt++)
        #pragma unroll
        for (int reg = 0; reg < 4; reg++) {
            int gr = r0 + rh + rt * 16 + q * 4 + reg;
            if (gr < M) {
                #pragma unroll
                for (int ct = 0; ct < 4; ct++)
                    P[(size_t)gr * 128 + ch + ct * 16 + lr] = bf16r(acc[rt][ct][reg]);
            }
        }
}

// ---------------------------------------------------------------------------
// MFMA GEMM, bf16 A: P = A @ Wt^T -> bf16.
// ---------------------------------------------------------------------------
__global__ __launch_bounds__(256) void gemm_mfma_bf16(
    const u16* __restrict__ A, const short* __restrict__ Wt,
    u16* __restrict__ P, int M)
{
    __shared__ short As[64 * 128];
    __shared__ short Ws[128 * 128];
    int t = threadIdx.x;
    int r0 = blockIdx.x * 64;
    for (int i = t; i < 64 * 16; i += 256) {
        int row = i >> 4, c16 = i & 15;
        int gr = r0 + row;
        uint4 u = make_uint4(0u, 0u, 0u, 0u);
        if (gr < M) u = *(const uint4*)((const char*)A + (size_t)gr * 256 + c16 * 16);
        *(uint4*)((char*)As + row * 256 + ((c16 * 16) ^ ((row & 7) << 4))) = u;
    }
    for (int i = t; i < 128 * 16; i += 256) {
        int row = i >> 4, c16 = i & 15;
        uint4 u = *(const uint4*)((const char*)Wt + row * 256 + c16 * 16);
        *(uint4*)((char*)Ws + row * 256 + ((c16 * 16) ^ ((row & 7) << 4))) = u;
    }
    __syncthreads();
    int w = t >> 6, l = t & 63, lr = l & 15, q = l >> 4;
    int rh = (w & 1) * 32, ch = (w >> 1) * 64;
    f32x4 acc[2][4];
    #pragma unroll
    for (int rt = 0; rt < 2; rt++)
        #pragma unroll
        for (int ct = 0; ct < 4; ct++) acc[rt][ct] = (f32x4){0.f, 0.f, 0.f, 0.f};
    #pragma unroll
    for (int kk = 0; kk < 4; kk++) {
        int bo = kk * 64 + q * 16;
        bf16x8 a[2];
        #pragma unroll
        for (int rt = 0; rt < 2; rt++) {
            int ar = rh + rt * 16 + lr;
            a[rt] = *(const bf16x8*)((const char*)As + ar * 256 + (bo ^ ((ar & 7) << 4)));
        }
        #pragma unroll
        for (int ct = 0; ct < 4; ct++) {
            int br = ch + ct * 16 + lr;
            bf16x8 b = *(const bf16x8*)((const char*)Ws + br * 256 + (bo ^ ((br & 7) << 4)));
            acc[0][ct] = __builtin_amdgcn_mfma_f32_16x16x32_bf16(a[0], b, acc[0][ct], 0, 0, 0);
            acc[1][ct] = __builtin_amdgcn_mfma_f32_16x16x32_bf16(a[1], b, acc[1][ct], 0, 0, 0);
        }
    }
    #pragma unroll
    for (int rt = 0; rt < 2; rt++)
        #pragma unroll
        for (int reg = 0; reg < 4; reg++) {
            int gr = r0 + rh + rt * 16 + q * 4 + reg;
            if (gr < M) {
                #pragma unroll
                for (int ct = 0; ct < 4; ct++)
                    P[(size_t)gr * 128 + ch + ct * 16 + lr] = bf16r(acc[rt][ct][reg]);
            }
        }
}

// ---------------------------------------------------------------------------
// X[w] = relu(segsum(P) + deg*bias). One node per 16-lane quarter; each lane
// owns 8 features (one uint4 of the row). No cross-lane reduce. 4-deep MLP.
// ---------------------------------------------------------------------------
__global__ __launch_bounds__(256) void agg_relu_q(
    const u16* __restrict__ P, const int* __restrict__ offp,
    const int* __restrict__ deg,
    const int* __restrict__ ids, const float* __restrict__ bias,
    u16* __restrict__ X, int M)
{
    int qid = threadIdx.x >> 4;          // 0..15
    int l = threadIdx.x & 15;
    int w = blockIdx.x * 16 + qid;
    if (w >= M) return;
    int beg = offp[w], end = beg + deg[w];
    const uint4* F = (const uint4*)P;
    float a0 = 0.f, a1 = 0.f, a2 = 0.f, a3 = 0.f,
          a4 = 0.f, a5 = 0.f, a6 = 0.f, a7 = 0.f;
    int i = beg;
    for (; i + 3 < end; i += 4) {
        uint4 v0 = F[(size_t)ids[i]     * 16 + l];
        uint4 v1 = F[(size_t)ids[i + 1] * 16 + l];
        uint4 v2 = F[(size_t)ids[i + 2] * 16 + l];
        uint4 v3 = F[(size_t)ids[i + 3] * 16 + l];
        a0 += bflo(v0.x) + bflo(v1.x) + bflo(v2.x) + bflo(v3.x);
        a1 += bfhi(v0.x) + bfhi(v1.x) + bfhi(v2.x) + bfhi(v3.x);
        a2 += bflo(v0.y) + bflo(v1.y) + bflo(v2.y) + bflo(v3.y);
        a3 += bfhi(v0.y) + bfhi(v1.y) + bfhi(v2.y) + bfhi(v3.y);
        a4 += bflo(v0.z) + bflo(v1.z) + bflo(v2.z) + bflo(v3.z);
        a5 += bfhi(v0.z) + bfhi(v1.z) + bfhi(v2.z) + bfhi(v3.z);
        a6 += bflo(v0.w) + bflo(v1.w) + bflo(v2.w) + bflo(v3.w);
        a7 += bfhi(v0.w) + bfhi(v1.w) + bfhi(v2.w) + bfhi(v3.w);
    }
    for (; i < end; i++) {
        uint4 v = F[(size_t)ids[i] * 16 + l];
        a0 += bflo(v.x); a1 += bfhi(v.x);
        a2 += bflo(v.y); a3 += bfhi(v.y);
        a4 += bflo(v.z); a5 += bfhi(v.z);
        a6 += bflo(v.w); a7 += bfhi(v.w);
    }
    float dg = (float)(end - beg);
    float4 b0 = ((const float4*)bias)[2 * l];
    float4 b1 = ((const float4*)bias)[2 * l + 1];
    a0 = fmaxf(fmaf(dg, b0.x, a0), 0.f);
    a1 = fmaxf(fmaf(dg, b0.y, a1), 0.f);
    a2 = fmaxf(fmaf(dg, b0.z, a2), 0.f);
    a3 = fmaxf(fmaf(dg, b0.w, a3), 0.f);
    a4 = fmaxf(fmaf(dg, b1.x, a4), 0.f);
    a5 = fmaxf(fmaf(dg, b1.y, a5), 0.f);
    a6 = fmaxf(fmaf(dg, b1.z, a6), 0.f);
    a7 = fmaxf(fmaf(dg, b1.w, a7), 0.f);
    uint4 o;
    o.x = pack2(a0, a1); o.y = pack2(a2, a3);
    o.z = pack2(a4, a5); o.w = pack2(a6, a7);
    ((uint4*)(X + (size_t)w * 128))[l] = o;
}

// ---------------------------------------------------------------------------
// Epilogue agg, one node per quarter: S[w] = x2[w] + segsum(x2) (bf16);
// Gg[w] = segsum_m(ef) (bf16). No cross-lane reduce.
// ---------------------------------------------------------------------------
__global__ __launch_bounds__(256) void agg_epilogue_q(
    const u16* __restrict__ X2, const float* __restrict__ ef,
    const int* __restrict__ offp, const int* __restrict__ deg,
    const int* __restrict__ ids,
    const int* __restrict__ offpm, const int* __restrict__ degm,
    const int* __restrict__ mids,
    u16* __restrict__ S, u16* __restrict__ Gg, int M)
{
    int qid = threadIdx.x >> 4;
    int l = threadIdx.x & 15;
    int w = blockIdx.x * 16 + qid;
    if (w >= M) return;
    // ---- node gather over X2 (own row + neighbors) ----
    {
        int beg = offp[w], end = beg + deg[w];
        const uint4* F = (const uint4*)X2;
        uint4 own = F[(size_t)w * 16 + l];
        float a0 = bflo(own.x), a1 = bfhi(own.x),
              a2 = bflo(own.y), a3 = bfhi(own.y),
              a4 = bflo(own.z), a5 = bfhi(own.z),
              a6 = bflo(own.w), a7 = bfhi(own.w);
        int i = beg;
        for (; i + 3 < end; i += 4) {
            uint4 v0 = F[(size_t)ids[i]     * 16 + l];
            uint4 v1 = F[(size_t)ids[i + 1] * 16 + l];
            uint4 v2 = F[(size_t)ids[i + 2] * 16 + l];
            uint4 v3 = F[(size_t)ids[i + 3] * 16 + l];
            a0 += bflo(v0.x) + bflo(v1.x) + bflo(v2.x) + bflo(v3.x);
            a1 += bfhi(v0.x) + bfhi(v1.x) + bfhi(v2.x) + bfhi(v3.x);
            a2 += bflo(v0.y) + bflo(v1.y) + bflo(v2.y) + bflo(v3.y);
            a3 += bfhi(v0.y) + bfhi(v1.y) + bfhi(v2.y) + bfhi(v3.y);
            a4 += bflo(v0.z) + bflo(v1.z) + bflo(v2.z) + bflo(v3.z);
            a5 += bfhi(v0.z) + bfhi(v1.z) + bfhi(v2.z) + bfhi(v3.z);
            a6 += bflo(v0.w) + bflo(v1.w) + bflo(v2.w) + bflo(v3.w);
            a7 += bfhi(v0.w) + bfhi(v1.w) + bfhi(v2.w) + bfhi(v3.w);
        }
        for (; i < end; i++) {
            uint4 v = F[(size_t)ids[i] * 16 + l];
            a0 += bflo(v.x); a1 += bfhi(v.x);
            a2 += bflo(v.y); a3 += bfhi(v.y);
            a4 += bflo(v.z); a5 += bfhi(v.z);
            a6 += bflo(v.w); a7 += bfhi(v.w);
        }
        uint4 o;
        o.x = pack2(a0, a1); o.y = pack2(a2, a3);
        o.z = pack2(a4, a5); o.w = pack2(a6, a7);
        ((uint4*)(S + (size_t)w * 128))[l] = o;
    }
    // ---- meta gather over ef (f32 rows, 16 float4) ----
    {
        int beg = offpm[w], end = beg + degm[w];
        const float4* E = (const float4*)ef;
        float g0 = 0.f, g1 = 0.f, g2 = 0.f, g3 = 0.f;
        int i = beg;
        for (; i + 3 < end; i += 4) {
            float4 v0 = E[(size_t)mids[i]     * 16 + l];
            float4 v1 = E[(size_t)mids[i + 1] * 16 + l];
            float4 v2 = E[(size_t)mids[i + 2] * 16 + l];
            float4 v3 = E[(size_t)mids[i + 3] * 16 + l];
            g0 += v0.x + v1.x + v2.x + v3.x;
            g1 += v0.y + v1.y + v2.y + v3.y;
            g2 += v0.z + v1.z + v2.z + v3.z;
            g3 += v0.w + v1.w + v2.w + v3.w;
        }
        for (; i < end; i++) {
            float4 v = E[(size_t)mids[i] * 16 + l];
            g0 += v.x; g1 += v.y; g2 += v.z; g3 += v.w;
        }
        uint2 o;
        o.x = pack2(g0, g1); o.y = pack2(g2, g3);
        ((uint2*)(Gg + (size_t)w * 64))[l] = o;
    }
}

// ---------------------------------------------------------------------------
// final MFMA GEMM: out = [S|Gg](64x192 bf16) @ Wft^T + cnt*bvec + bfc (f32).
// ---------------------------------------------------------------------------
__global__ __launch_bounds__(256) void final_mfma(
    const u16* __restrict__ S, const u16* __restrict__ Gg,
    const int* __restrict__ degm, const short* __restrict__ Wft,
    const float* __restrict__ bvec, const float* __restrict__ bfc,
    float* __restrict__ out, int M)
{
    __shared__ short As[64 * 192];   // 24 KB, row stride 384B
    __shared__ short Ws[64 * 192];   // 24 KB
    int t = threadIdx.x;
    int r0 = blockIdx.x * 64;
    for (int i = t; i < 64 * 16; i += 256) {      // S half: bytes [0,256)/row
        int row = i >> 4, c16 = i & 15;
        int gr = r0 + row;
        uint4 u = make_uint4(0u, 0u, 0u, 0u);
        if (gr < M) u = *(const uint4*)((const char*)S + (size_t)gr * 256 + c16 * 16);
        *(uint4*)((char*)As + row * 384 + ((c16 * 16) ^ ((row & 7) << 4))) = u;
    }
    for (int i = t; i < 64 * 8; i += 256) {       // Gg half: bytes [256,384)/row
        int row = i >> 3, c16 = i & 7;
        int gr = r0 + row;
        uint4 u = make_uint4(0u, 0u, 0u, 0u);
        if (gr < M) u = *(const uint4*)((const char*)Gg + (size_t)gr * 128 + c16 * 16);
        *(uint4*)((char*)As + row * 384 + ((256 + c16 * 16) ^ ((row & 7) << 4))) = u;
    }
    for (int i = t; i < 64 * 24; i += 256) {      // Wft: 24 chunks/row (384B)
        int row = i / 24, c16 = i - row * 24;
        uint4 u = *(const uint4*)((const char*)Wft + row * 384 + c16 * 16);
        *(uint4*)((char*)Ws + row * 384 + ((c16 * 16) ^ ((row & 7) << 4))) = u;
    }
    __syncthreads();
    int w = t >> 6, l = t & 63, lr = l & 15, q = l >> 4;
    int rh = (w & 1) * 32, ch = (w >> 1) * 32;
    f32x4 acc[2][2];
    #pragma unroll
    for (int rt = 0; rt < 2; rt++)
        #pragma unroll
        for (int ct = 0; ct < 2; ct++) acc[rt][ct] = (f32x4){0.f, 0.f, 0.f, 0.f};
    #pragma unroll
    for (int kk = 0; kk < 6; kk++) {
        int bo = kk * 64 + q * 16;
        bf16x8 a[2];
        #pragma unroll
        for (int rt = 0; rt < 2; rt++) {
            int ar = rh + rt * 16 + lr;
            a[rt] = *(const bf16x8*)((const char*)As + ar * 384 + (bo ^ ((ar & 7) << 4)));
        }
        #pragma unroll
        for (int ct = 0; ct < 2; ct++) {
            int br = ch + ct * 16 + lr;
            bf16x8 b = *(const bf16x8*)((const char*)Ws + br * 384 + (bo ^ ((br & 7) << 4)));
            acc[0][ct] = __builtin_amdgcn_mfma_f32_16x16x32_bf16(a[0], b, acc[0][ct], 0, 0, 0);
            acc[1][ct] = __builtin_amdgcn_mfma_f32_16x16x32_bf16(a[1], b, acc[1][ct], 0, 0, 0);
        }
    }
    float bv0 = bvec[ch + lr], bv1 = bvec[ch + 16 + lr];
    float bf0 = bfc[ch + lr],  bf1 = bfc[ch + 16 + lr];
    #pragma unroll
    for (int rt = 0; rt < 2; rt++)
        #pragma unroll
        for (int reg = 0; reg < 4; reg++) {
            int gr = r0 + rh + rt * 16 + q * 4 + reg;
            if (gr < M) {
                float cnt = (float)degm[gr];
                out[(size_t)gr * 64 + ch + lr]      = acc[rt][0][reg] + fmaf(cnt, bv0, bf0);
                out[(size_t)gr * 64 + ch + 16 + lr] = acc[rt][1][reg] + fmaf(cnt, bv1, bf1);
            }
        }
}

extern "C" void kernel_launch(void* const* d_in, const int* in_sizes, int n_in,
                              void* d_out, int out_size, void* d_ws, size_t ws_size,
                              hipStream_t stream)
{
    const float* nf  = (const float*)d_in[0];
    const int*   ei  = (const int*)d_in[1];
    const float* ef  = (const float*)d_in[2];
    const int*   emi = (const int*)d_in[3];
    const float* W1  = (const float*)d_in[4];
    const float* b1  = (const float*)d_in[5];
    const float* W2  = (const float*)d_in[6];
    const float* b2  = (const float*)d_in[7];
    const float* We  = (const float*)d_in[8];
    const float* be  = (const float*)d_in[9];
    const float* Wfc = (const float*)d_in[10];
    const float* bfc = (const float*)d_in[11];

    const int* row  = ei;
    const int* col  = ei + N_EDGES;
    const int* mrow = emi;
    const int* mcol = emi + N_EDGES;

    // ---- workspace layout ----
    u16* A  = (u16*)d_ws;                          // 50000*128 bf16
    u16* B  = A + (size_t)N_NODES * 128;
    u16* S  = B + (size_t)N_NODES * 128;
    u16* Gg = S + (size_t)N_NODES * 128;           // 50000*64
    u32* pairs  = (u32*)(Gg + (size_t)N_NODES * 64);       // NBKT*CAP
    u32* pairsm = pairs + (size_t)NBKT * CAP;
    float* Wcomb = (float*)(pairsm + (size_t)NBKT * CAP);  // 64*64
    float* bvec  = Wcomb + 64 * 64;                        // 64
    short* W1t = (short*)(bvec + 64);              // 128*128 bf16
    short* W2t = W1t + 128 * 128;
    short* Wft = W2t + 128 * 128;                  // 64*192 bf16
    int* offp  = (int*)(Wft + 64 * 192);           // N
    int* deg   = offp + N_NODES;
    int* offpm = deg + N_NODES;
    int* degm  = offpm + N_NODES;
    int* bcur  = degm + N_NODES;                   // 256
    int* bcurm = bcur + 256;
    int* ids   = bcurm + 256;                      // NBKT*CAP
    int* idsm  = ids + (size_t)NBKT * CAP;

    // weights precompute + cursor init
    pre1<<<146, 256, 0, stream>>>(We, be, Wfc, W1, W2, Wcomb, bvec, W1t, W2t, bcur, bcurm);

    // CSR build via bucket multisplit
    bin_pairs<<<2 * NBLK1, 256, 0, stream>>>(row, col, mrow, mcol,
                                             bcur, bcurm, pairs, pairsm);
    bucket_fill<<<2 * NBKT, 256, 0, stream>>>(pairs, pairsm, bcur, bcurm,
                                              offp, deg, ids, offpm, degm, idsm);
    pre2<<<48, 256, 0, stream>>>(Wfc, Wcomb, Wft);

    // P1 = nf @ W1 (bf16, MFMA)
    gemm_mfma_f32<<<(N_NODES + 63) / 64, 256, 0, stream>>>(nf, W1t, A, N_NODES);
    // x1 = relu(segsum(P1) + deg b1)
    agg_relu_q<<<(N_NODES + 15) / 16, 256, 0, stream>>>(A, offp, deg, ids, b1, B, N_NODES);
    // P2 = x1 @ W2 (MFMA)
    gemm_mfma_bf16<<<(N_NODES + 63) / 64, 256, 0, stream>>>(B, W2t, A, N_NODES);
    // x2 = relu(segsum(P2) + deg b2)
    agg_relu_q<<<(N_NODES + 15) / 16, 256, 0, stream>>>(A, offp, deg, ids, b2, B, N_NODES);
    // S = x2 + agg(x2); Gg = agg_m(ef)
    agg_epilogue_q<<<(N_NODES + 15) / 16, 256, 0, stream>>>(
        B, ef, offp, deg, ids, offpm, degm, idsm, S, Gg, N_NODES);
    // out = [S|Gg] @ Wft^T + cnt bvec + bfc (MFMA)
    final_mfma<<<(N_NODES + 63) / 64, 256, 0, stream>>>(
        S, Gg, degm, Wft, bvec, bfc, (float*)d_out, N_NODES);
}